// Round 6
// baseline (923.307 us; speedup 1.0000x reference)
//
#include <hip/hip_runtime.h>
#include <hip/hip_bf16.h>
#include <cstddef>

// ---------------- zero fill (graph-capture-safe memset) ----------------

__global__ void k_zero_i(int* __restrict__ p, int total) {
    int i = blockIdx.x * blockDim.x + threadIdx.x;
    int stride = gridDim.x * blockDim.x;
    for (; i < total; i += stride) p[i] = 0;
}

// ---------------- degree / norm ----------------

__global__ void k_deg_i(const int* __restrict__ dst, int* __restrict__ deg, int E) {
    int e = blockIdx.x * blockDim.x + threadIdx.x;
    if (e < E) atomicAdd(&deg[dst[e]], 1);
}

__global__ void k_dinv(const int* __restrict__ deg, float* __restrict__ dinv, int N) {
    int i = blockIdx.x * blockDim.x + threadIdx.x;
    if (i < N) dinv[i] = rsqrtf((float)deg[i] + 1.0f);
}

// ---------------- exclusive scan (3-phase, N <= 1024*1024) ----------------

#define SCAN_B 1024

__global__ void k_scan1(const int* __restrict__ in, int* __restrict__ out,
                        int* __restrict__ sums, int n) {
    __shared__ int tmp[SCAN_B];
    int tid = threadIdx.x;
    int gid = blockIdx.x * SCAN_B + tid;
    int v = (gid < n) ? in[gid] : 0;
    tmp[tid] = v;
    __syncthreads();
    for (int off = 1; off < SCAN_B; off <<= 1) {
        int t = (tid >= off) ? tmp[tid - off] : 0;
        __syncthreads();
        tmp[tid] += t;
        __syncthreads();
    }
    if (gid < n) out[gid] = tmp[tid] - v;          // exclusive
    if (tid == SCAN_B - 1) sums[blockIdx.x] = tmp[tid];
}

__global__ void k_scan2(int* __restrict__ sums, int nb) {
    __shared__ int tmp[128];
    int tid = threadIdx.x;
    int v = (tid < nb) ? sums[tid] : 0;
    tmp[tid] = v;
    __syncthreads();
    for (int off = 1; off < 128; off <<= 1) {
        int t = (tid >= off) ? tmp[tid - off] : 0;
        __syncthreads();
        tmp[tid] += t;
        __syncthreads();
    }
    if (tid < nb) sums[tid] = tmp[tid] - v;        // exclusive block offsets
}

__global__ void k_scan3(int* __restrict__ out, int* __restrict__ cursor,
                        const int* __restrict__ sums, int n) {
    int gid = blockIdx.x * SCAN_B + threadIdx.x;
    if (gid < n) {
        int v = out[gid] + sums[blockIdx.x];
        out[gid] = v;
        cursor[gid] = v;
    }
}

// ---------------- CSR fill ----------------

__global__ void k_fill(const int* __restrict__ src, const int* __restrict__ dst,
                       int* __restrict__ cursor, int* __restrict__ csr_src, int E) {
    int e = blockIdx.x * blockDim.x + threadIdx.x;
    if (e < E) {
        int pos = atomicAdd(&cursor[dst[e]], 1);
        csr_src[pos] = src[e];
    }
}

// ---------------- fused gather aggregation + self-loop + bias + relu ----------
// out[n] = relu( sum_{s in in(n)} h[s]*dinv[s]*dinv[n] + h[n]*dinv[n]^2 + bias )
// One wave per node. F=128: 32 lanes/edge (float4), 2 edges per step, 2-unrolled.
// F=64: 16 lanes/edge (float4), 4 edges per step, 2-unrolled.

__device__ __forceinline__ float4 shfl_xor4(float4 v, int m) {
    return make_float4(__shfl_xor(v.x, m), __shfl_xor(v.y, m),
                       __shfl_xor(v.z, m), __shfl_xor(v.w, m));
}

__device__ __forceinline__ void fmaa4(float4& c, float w, const float4& v) {
    c.x = fmaf(w, v.x, c.x);
    c.y = fmaf(w, v.y, c.y);
    c.z = fmaf(w, v.z, c.z);
    c.w = fmaf(w, v.w, c.w);
}

template<int F>
__launch_bounds__(256)
__global__ void k_gather(const float* __restrict__ h, const int* __restrict__ csr_src,
                         const int* __restrict__ off, const float* __restrict__ dinv,
                         const float* __restrict__ bias, float* __restrict__ out,
                         int N, int E)
{
    int node = blockIdx.x * (blockDim.x / 64) + (threadIdx.x >> 6);
    int lane = threadIdx.x & 63;
    if (node >= N) return;
    float dn = dinv[node];
    int beg = off[node];
    int end = (node + 1 < N) ? off[node + 1] : E;

    constexpr int G = (F == 128) ? 2 : 4;      // edge groups per wave
    constexpr int SUBW = 64 / G;               // lanes per edge
    const int grp = lane / SUBW;
    const int sub = lane % SUBW;               // covers F/4 float4 slots? F/SUBW floats
    // per-lane float4 slot within a row:
    // F==128: sub in [0,32) -> floats sub*4..sub*4+3
    // F==64 : sub in [0,16) -> floats sub*4..sub*4+3

    float4 acc = make_float4(0.f, 0.f, 0.f, 0.f);
    int i = beg + grp;
    // 2-unrolled: each group handles edges i, i+G per iteration
    for (; i + G < end; i += 2 * G) {
        int s0 = csr_src[i];
        int s1 = csr_src[i + G];
        float w0 = dinv[s0] * dn;
        float w1 = dinv[s1] * dn;
        float4 v0 = *(const float4*)(h + (size_t)s0 * F + sub * 4);
        float4 v1 = *(const float4*)(h + (size_t)s1 * F + sub * 4);
        fmaa4(acc, w0, v0);
        fmaa4(acc, w1, v1);
    }
    if (i < end) {
        int s = csr_src[i];
        float w = dinv[s] * dn;
        float4 v = *(const float4*)(h + (size_t)s * F + sub * 4);
        fmaa4(acc, w, v);
    }

    // cross-group reduce: after these, every lane holds the full sum
    if (F == 64) acc = make_float4(acc.x + __shfl_xor(acc.x, 16),
                                   acc.y + __shfl_xor(acc.y, 16),
                                   acc.z + __shfl_xor(acc.z, 16),
                                   acc.w + __shfl_xor(acc.w, 16));
    {
        float4 o = shfl_xor4(acc, 32);
        acc.x += o.x; acc.y += o.y; acc.z += o.z; acc.w += o.w;
    }

    if (grp == 0) {
        float4 hv = *(const float4*)(h + (size_t)node * F + sub * 4);
        float4 bv = *(const float4*)(bias + sub * 4);
        float w = dn * dn;
        acc.x = fmaxf(fmaf(hv.x, w, acc.x) + bv.x, 0.f);
        acc.y = fmaxf(fmaf(hv.y, w, acc.y) + bv.y, 0.f);
        acc.z = fmaxf(fmaf(hv.z, w, acc.z) + bv.z, 0.f);
        acc.w = fmaxf(fmaf(hv.w, w, acc.w) + bv.w, 0.f);
        *(float4*)(out + (size_t)node * F + sub * 4) = acc;
    }
}

// ---------------- wave-tile fp32 GEMM ----------------
// C[M,N] = A[M,K] @ B[K,N] (+bias). 256 threads = 4 waves arranged WR x WC,
// each wave owns a 64x64 tile. Lane l = (l%8, l/8); each lane computes four
// 4x4 blocks at (+0/+32, +0/+32). Inner-loop LDS reads are aligned
// ds_read_b128, conflict-free. Grid: x = N-blocks, y = M-blocks (so the
// blocks sharing one A row-panel dispatch consecutively -> L2/L3-warm A).
// K must be a multiple of BK.

__device__ __forceinline__ void fma4(float4& c, float a, const float4& b) {
    c.x = fmaf(a, b.x, c.x);
    c.y = fmaf(a, b.y, c.y);
    c.z = fmaf(a, b.z, c.z);
    c.w = fmaf(a, b.w, c.w);
}

template<int WR, int WC, int BK>
__launch_bounds__(256)
__global__ void gemm_wt(const float* __restrict__ A, const float* __restrict__ B,
                        const float* __restrict__ bias, float* __restrict__ C,
                        int M, int N, int K)
{
    constexpr int BM = WR * 64;
    constexpr int BN = WC * 64;
    constexpr int LDA = BM + 4;            // +4 keeps 16B alignment; staging-write
    __shared__ float As[BK * LDA];         // conflicts are ~3% of cycles (measured), ok
    __shared__ float Bs[BK * BN];

    const int tid  = threadIdx.x;
    const int wave = tid >> 6, lane = tid & 63;
    const int wr = wave / WC, wc = wave % WC;
    const int ar = wr * 64 + (lane & 7) * 4;
    const int bc = wc * 64 + (lane >> 3) * 4;
    const int m0 = blockIdx.y * BM;
    const int n0 = blockIdx.x * BN;

    float4 acc[2][2][4];
#pragma unroll
    for (int i = 0; i < 2; ++i)
#pragma unroll
        for (int j = 0; j < 2; ++j)
#pragma unroll
            for (int r = 0; r < 4; ++r) acc[i][j][r] = make_float4(0.f, 0.f, 0.f, 0.f);

    constexpr int AC4   = BK / 4;          // float4 slots per A row chunk
    constexpr int AROWS = 256 / AC4;
    const int a_c4 = tid % AC4;
    const int a_m  = tid / AC4;
    constexpr int BC4   = BN / 4;
    constexpr int BROWS = 256 / BC4;
    const int b_c4 = tid % BC4;
    const int b_r  = tid / BC4;

    for (int k0 = 0; k0 < K; k0 += BK) {
        // ---- stage A tile transposed: As[k][m] = A[m0+m][k0+k] ----
#pragma unroll
        for (int p = 0; p < BM / AROWS; ++p) {
            int m = a_m + p * AROWS;
            int gr = m0 + m;
            float4 v = make_float4(0.f, 0.f, 0.f, 0.f);
            if (gr < M) v = *(const float4*)(A + (size_t)gr * K + k0 + 4 * a_c4);
            As[(4 * a_c4 + 0) * LDA + m] = v.x;
            As[(4 * a_c4 + 1) * LDA + m] = v.y;
            As[(4 * a_c4 + 2) * LDA + m] = v.z;
            As[(4 * a_c4 + 3) * LDA + m] = v.w;
        }
        // ---- stage B tile ----
#pragma unroll
        for (int p = 0; p < BK / BROWS; ++p) {
            int r = b_r + p * BROWS;
            int gc = n0 + 4 * b_c4;
            const float* Brow = B + (size_t)(k0 + r) * N;
            float4 v = make_float4(0.f, 0.f, 0.f, 0.f);
            if (gc + 3 < N) {
                v = *(const float4*)(Brow + gc);
            } else {
                if (gc + 0 < N) v.x = Brow[gc + 0];
                if (gc + 1 < N) v.y = Brow[gc + 1];
                if (gc + 2 < N) v.z = Brow[gc + 2];
            }
            *(float4*)&Bs[r * BN + 4 * b_c4] = v;
        }
        __syncthreads();

#pragma unroll 8
        for (int kk = 0; kk < BK; ++kk) {
            const float* as = &As[kk * LDA];
            const float* bs = &Bs[kk * BN];
            float4 a0 = *(const float4*)(as + ar);
            float4 a1 = *(const float4*)(as + ar + 32);
            float4 b0 = *(const float4*)(bs + bc);
            float4 b1 = *(const float4*)(bs + bc + 32);
            float ae0[4] = {a0.x, a0.y, a0.z, a0.w};
            float ae1[4] = {a1.x, a1.y, a1.z, a1.w};
#pragma unroll
            for (int r = 0; r < 4; ++r) {
                fma4(acc[0][0][r], ae0[r], b0);
                fma4(acc[0][1][r], ae0[r], b1);
                fma4(acc[1][0][r], ae1[r], b0);
                fma4(acc[1][1][r], ae1[r], b1);
            }
        }
        __syncthreads();
    }

    // ---- epilogue ----
#pragma unroll
    for (int i = 0; i < 2; ++i)
#pragma unroll
        for (int r = 0; r < 4; ++r) {
            int gr = m0 + ar + 32 * i + r;
            if (gr >= M) continue;
#pragma unroll
            for (int j = 0; j < 2; ++j) {
                int gc = n0 + bc + 32 * j;
                float4 v = acc[i][j][r];
                if (gc + 3 < N) {
                    if (bias) {
                        v.x += bias[gc + 0];
                        v.y += bias[gc + 1];
                        v.z += bias[gc + 2];
                        v.w += bias[gc + 3];
                    }
                    *(float4*)(C + (size_t)gr * N + gc) = v;
                } else {
                    float vv[4] = {v.x, v.y, v.z, v.w};
#pragma unroll
                    for (int e = 0; e < 4; ++e)
                        if (gc + e < N)
                            C[(size_t)gr * N + gc + e] = vv[e] + (bias ? bias[gc + e] : 0.f);
                }
            }
        }
}

// ---------------- launch ----------------
// Harness passes integer inputs as int32. d_out (400 MB) doubles as scratch:
//   O0 h[N,128] | O1 h1[N,128] | O2 h2pre[N,64] | csr_src[E] | offs[N]
//   cursor[N] | deg_cnt[N] | bsums[128]          (all dead before final GEMM)
// d_ws: [dinv 0.5MB][h2 25.6MB] — h2 must survive the final GEMM's d_out writes.

extern "C" void kernel_launch(void* const* d_in, const int* in_sizes, int n_in,
                              void* d_out, int out_size, void* d_ws, size_t ws_size,
                              hipStream_t stream)
{
    const float* x   = (const float*)d_in[0];
    const float* W1  = (const float*)d_in[1];
    const float* b1  = (const float*)d_in[2];
    const float* W2  = (const float*)d_in[3];
    const float* b2  = (const float*)d_in[4];
    const float* Wfc = (const float*)d_in[5];
    const float* bfc = (const float*)d_in[6];
    const int*   ei  = (const int*)d_in[7];     // int32 in the harness

    const int Nn = in_sizes[0] / 128;      // 100000 nodes
    const int E  = in_sizes[7] / 2;        // 1600000 edges
    const int* src = ei;
    const int* dst = ei + E;

    char* ws = (char*)d_ws;
    float* dinv = (float*)(ws);                        // Nn floats
    float* h2   = (float*)(ws + 512 * 1024);           // Nn*64 floats (25.6 MB)

    float* out = (float*)d_out;
    float* O0      = out;                              // h [Nn,128]
    float* O1      = out + (size_t)Nn * 128;           // h1 [Nn,128]
    float* O2      = out + (size_t)Nn * 256;           // h2pre [Nn,64]
    int*   csr_src = (int*)(out + (size_t)Nn * 320);   // E ints
    int*   offs    = (int*)((char*)csr_src + (size_t)E * 4);
    int*   cursor  = (int*)((char*)offs + (size_t)Nn * 4);
    int*   deg_cnt = (int*)((char*)cursor + (size_t)Nn * 4);
    int*   bsums   = (int*)((char*)deg_cnt + (size_t)Nn * 4);

    const int nScanBlocks = (Nn + SCAN_B - 1) / SCAN_B;   // 98 <= 128

    // ---- degree, dinv, offsets, cursor ----
    k_zero_i<<<128, 256, 0, stream>>>(deg_cnt, Nn);
    k_deg_i<<<(E + 255) / 256, 256, 0, stream>>>(dst, deg_cnt, E);
    k_dinv<<<(Nn + 255) / 256, 256, 0, stream>>>(deg_cnt, dinv, Nn);
    k_scan1<<<nScanBlocks, SCAN_B, 0, stream>>>(deg_cnt, offs, bsums, Nn);
    k_scan2<<<1, 128, 0, stream>>>(bsums, nScanBlocks);
    k_scan3<<<nScanBlocks, SCAN_B, 0, stream>>>(offs, cursor, bsums, Nn);

    // ---- CSR fill ----
    k_fill<<<(E + 255) / 256, 256, 0, stream>>>(src, dst, cursor, csr_src, E);

    // ---- layer 1 ----
    // h = x @ W1 -> O0    (K=128, 2 phases of BK=64)
    gemm_wt<2, 2, 64><<<dim3(1, (Nn + 127) / 128), 256, 0, stream>>>(
        x, W1, nullptr, O0, Nn, 128, 128);
    // h1 = relu(gather(h) + self + b1) -> O1
    k_gather<128><<<(Nn + 3) / 4, 256, 0, stream>>>(O0, csr_src, offs, dinv, b1, O1, Nn, E);

    // ---- layer 2 ----
    // h2pre = h1 @ W2 -> O2   (BM=256, N=64)
    gemm_wt<4, 1, 32><<<dim3(1, (Nn + 255) / 256), 256, 0, stream>>>(
        O1, W2, nullptr, O2, Nn, 64, 128);
    // h2 = relu(gather(h2pre) + self + b2) -> ws
    k_gather<64><<<(Nn + 3) / 4, 256, 0, stream>>>(O2, csr_src, offs, dinv, b2, h2, Nn, E);

    // ---- output layer: out = h2 @ Wfc + bfc (K=64: single-phase blocks) ----
    gemm_wt<2, 2, 64><<<dim3((1000 + 127) / 128, (Nn + 127) / 128), 256, 0, stream>>>(
        h2, Wfc, bfc, out, Nn, 1000, 64);
}

// Round 7
// 722.769 us; speedup vs baseline: 1.2775x; 1.2775x over previous
//
#include <hip/hip_runtime.h>
#include <hip/hip_bf16.h>
#include <cstddef>

// ---------------- zero fill (graph-capture-safe memset) ----------------

__global__ void k_zero_i(int* __restrict__ p, int total) {
    int i = blockIdx.x * blockDim.x + threadIdx.x;
    int stride = gridDim.x * blockDim.x;
    for (; i < total; i += stride) p[i] = 0;
}

// ---------------- degree / norm ----------------

__global__ void k_deg_i(const int* __restrict__ dst, int* __restrict__ deg, int E) {
    int e = blockIdx.x * blockDim.x + threadIdx.x;
    if (e < E) atomicAdd(&deg[dst[e]], 1);
}

__global__ void k_dinv(const int* __restrict__ deg, float* __restrict__ dinv, int N) {
    int i = blockIdx.x * blockDim.x + threadIdx.x;
    if (i < N) dinv[i] = rsqrtf((float)deg[i] + 1.0f);
}

// ---------------- exclusive scan (3-phase, N <= 1024*1024) ----------------

#define SCAN_B 1024

__global__ void k_scan1(const int* __restrict__ in, int* __restrict__ out,
                        int* __restrict__ sums, int n) {
    __shared__ int tmp[SCAN_B];
    int tid = threadIdx.x;
    int gid = blockIdx.x * SCAN_B + tid;
    int v = (gid < n) ? in[gid] : 0;
    tmp[tid] = v;
    __syncthreads();
    for (int off = 1; off < SCAN_B; off <<= 1) {
        int t = (tid >= off) ? tmp[tid - off] : 0;
        __syncthreads();
        tmp[tid] += t;
        __syncthreads();
    }
    if (gid < n) out[gid] = tmp[tid] - v;          // exclusive
    if (tid == SCAN_B - 1) sums[blockIdx.x] = tmp[tid];
}

__global__ void k_scan2(int* __restrict__ sums, int nb) {
    __shared__ int tmp[128];
    int tid = threadIdx.x;
    int v = (tid < nb) ? sums[tid] : 0;
    tmp[tid] = v;
    __syncthreads();
    for (int off = 1; off < 128; off <<= 1) {
        int t = (tid >= off) ? tmp[tid - off] : 0;
        __syncthreads();
        tmp[tid] += t;
        __syncthreads();
    }
    if (tid < nb) sums[tid] = tmp[tid] - v;        // exclusive block offsets
}

__global__ void k_scan3(int* __restrict__ out, int* __restrict__ cursor,
                        const int* __restrict__ sums, int n) {
    int gid = blockIdx.x * SCAN_B + threadIdx.x;
    if (gid < n) {
        int v = out[gid] + sums[blockIdx.x];
        out[gid] = v;
        cursor[gid] = v;
    }
}

// ---------------- CSR fill ----------------

__global__ void k_fill(const int* __restrict__ src, const int* __restrict__ dst,
                       int* __restrict__ cursor, int* __restrict__ csr_src, int E) {
    int e = blockIdx.x * blockDim.x + threadIdx.x;
    if (e < E) {
        int pos = atomicAdd(&cursor[dst[e]], 1);
        csr_src[pos] = src[e];
    }
}

// ---------------- fused gather aggregation + self-loop + bias + relu ----------
// out[n] = relu( sum_{s in in(n)} h[s]*dinv[s]*dinv[n] + h[n]*dinv[n]^2 + bias )
// One wave per node. F=128: 32 lanes/edge (float4), 2 edges per step, 2-unrolled.
// F=64: 16 lanes/edge (float4), 4 edges per step, 2-unrolled.

__device__ __forceinline__ float4 shfl_xor4(float4 v, int m) {
    return make_float4(__shfl_xor(v.x, m), __shfl_xor(v.y, m),
                       __shfl_xor(v.z, m), __shfl_xor(v.w, m));
}

__device__ __forceinline__ void fmaa4(float4& c, float w, const float4& v) {
    c.x = fmaf(w, v.x, c.x);
    c.y = fmaf(w, v.y, c.y);
    c.z = fmaf(w, v.z, c.z);
    c.w = fmaf(w, v.w, c.w);
}

template<int F>
__launch_bounds__(256)
__global__ void k_gather(const float* __restrict__ h, const int* __restrict__ csr_src,
                         const int* __restrict__ off, const float* __restrict__ dinv,
                         const float* __restrict__ bias, float* __restrict__ out,
                         int N, int E)
{
    int node = blockIdx.x * (blockDim.x / 64) + (threadIdx.x >> 6);
    int lane = threadIdx.x & 63;
    if (node >= N) return;
    float dn = dinv[node];
    int beg = off[node];
    int end = (node + 1 < N) ? off[node + 1] : E;

    constexpr int G = (F == 128) ? 2 : 4;      // edge groups per wave
    constexpr int SUBW = 64 / G;               // lanes per edge
    const int grp = lane / SUBW;
    const int sub = lane % SUBW;

    float4 acc = make_float4(0.f, 0.f, 0.f, 0.f);
    int i = beg + grp;
    for (; i + G < end; i += 2 * G) {
        int s0 = csr_src[i];
        int s1 = csr_src[i + G];
        float w0 = dinv[s0] * dn;
        float w1 = dinv[s1] * dn;
        float4 v0 = *(const float4*)(h + (size_t)s0 * F + sub * 4);
        float4 v1 = *(const float4*)(h + (size_t)s1 * F + sub * 4);
        fmaa4(acc, w0, v0);
        fmaa4(acc, w1, v1);
    }
    if (i < end) {
        int s = csr_src[i];
        float w = dinv[s] * dn;
        float4 v = *(const float4*)(h + (size_t)s * F + sub * 4);
        fmaa4(acc, w, v);
    }

    // cross-group reduce: after these, every lane holds the full sum
    if (F == 64) acc = make_float4(acc.x + __shfl_xor(acc.x, 16),
                                   acc.y + __shfl_xor(acc.y, 16),
                                   acc.z + __shfl_xor(acc.z, 16),
                                   acc.w + __shfl_xor(acc.w, 16));
    {
        float4 o = shfl_xor4(acc, 32);
        acc.x += o.x; acc.y += o.y; acc.z += o.z; acc.w += o.w;
    }

    if (grp == 0) {
        float4 hv = *(const float4*)(h + (size_t)node * F + sub * 4);
        float4 bv = *(const float4*)(bias + sub * 4);
        float w = dn * dn;
        acc.x = fmaxf(fmaf(hv.x, w, acc.x) + bv.x, 0.f);
        acc.y = fmaxf(fmaf(hv.y, w, acc.y) + bv.y, 0.f);
        acc.z = fmaxf(fmaf(hv.z, w, acc.z) + bv.z, 0.f);
        acc.w = fmaxf(fmaf(hv.w, w, acc.w) + bv.w, 0.f);
        *(float4*)(out + (size_t)node * F + sub * 4) = acc;
    }
}

// ---------------- wave-tile fp32 GEMM ----------------
// C[M,N] = A[M,K] @ B[K,N] (+bias). 256 threads = 4 waves arranged WR x WC.
// Wave tile = (32*RM) x (32*RN); lane l = (l%8 -> row quad, l/8 -> col quad),
// computing RM x RN 4x4 sub-blocks at offsets (+32*i, +32*j). All inner-loop
// LDS reads are aligned ds_read_b128, conflict-free (8 distinct addrs x
// 8-lane broadcast). RM=4 halves LDS bytes per FMA vs RM=2 (LDS-BW was the
// measured limiter: 4KB/wave per 128 VALU-cyc -> 128B/cyc demand vs 85
// achievable). BK=32 keeps LDS <= 50KB -> 3 blocks/CU (BK=64 regressed:
// occupancy 21.9%->11.6%, dur 260->424us). K must be a multiple of BK.

__device__ __forceinline__ void fma4(float4& c, float a, const float4& b) {
    c.x = fmaf(a, b.x, c.x);
    c.y = fmaf(a, b.y, c.y);
    c.z = fmaf(a, b.z, c.z);
    c.w = fmaf(a, b.w, c.w);
}

template<int WR, int WC, int BK, int RM, int RN>
__launch_bounds__(256, 2)
__global__ void gemm_wt(const float* __restrict__ A, const float* __restrict__ B,
                        const float* __restrict__ bias, float* __restrict__ C,
                        int M, int N, int K)
{
    constexpr int TMW = 32 * RM;           // wave tile rows
    constexpr int TNW = 32 * RN;           // wave tile cols
    constexpr int BM = WR * TMW;
    constexpr int BN = WC * TNW;
    constexpr int LDA = BM + 4;            // +4 keeps 16B alignment, reads stay conflict-free
    __shared__ float As[BK * LDA];         // As[k][m]
    __shared__ float Bs[BK * BN];          // Bs[k][n]

    const int tid  = threadIdx.x;
    const int wave = tid >> 6, lane = tid & 63;
    const int wr = wave / WC, wc = wave % WC;
    const int ar = wr * TMW + (lane & 7) * 4;
    const int bc = wc * TNW + (lane >> 3) * 4;
    const int m0 = blockIdx.x * BM;
    const int n0 = blockIdx.y * BN;

    float4 acc[RM][RN][4];
#pragma unroll
    for (int i = 0; i < RM; ++i)
#pragma unroll
        for (int j = 0; j < RN; ++j)
#pragma unroll
            for (int r = 0; r < 4; ++r) acc[i][j][r] = make_float4(0.f, 0.f, 0.f, 0.f);

    constexpr int AC4   = BK / 4;
    constexpr int AROWS = 256 / AC4;
    const int a_c4 = tid % AC4;
    const int a_m  = tid / AC4;
    constexpr int BC4   = BN / 4;
    constexpr int BROWS = 256 / BC4;
    const int b_c4 = tid % BC4;
    const int b_r  = tid / BC4;

    for (int k0 = 0; k0 < K; k0 += BK) {
        // ---- stage A tile transposed: As[k][m] = A[m0+m][k0+k] ----
#pragma unroll
        for (int p = 0; p < BM / AROWS; ++p) {
            int m = a_m + p * AROWS;
            int gr = m0 + m;
            float4 v = make_float4(0.f, 0.f, 0.f, 0.f);
            if (gr < M) v = *(const float4*)(A + (size_t)gr * K + k0 + 4 * a_c4);
            As[(4 * a_c4 + 0) * LDA + m] = v.x;
            As[(4 * a_c4 + 1) * LDA + m] = v.y;
            As[(4 * a_c4 + 2) * LDA + m] = v.z;
            As[(4 * a_c4 + 3) * LDA + m] = v.w;
        }
        // ---- stage B tile ----
#pragma unroll
        for (int p = 0; p < BK / BROWS; ++p) {
            int r = b_r + p * BROWS;
            int gc = n0 + 4 * b_c4;
            const float* Brow = B + (size_t)(k0 + r) * N;
            float4 v = make_float4(0.f, 0.f, 0.f, 0.f);
            if (gc + 3 < N) {
                v = *(const float4*)(Brow + gc);
            } else {
                if (gc + 0 < N) v.x = Brow[gc + 0];
                if (gc + 1 < N) v.y = Brow[gc + 1];
                if (gc + 2 < N) v.z = Brow[gc + 2];
            }
            *(float4*)&Bs[r * BN + 4 * b_c4] = v;
        }
        __syncthreads();

#pragma unroll 8
        for (int kk = 0; kk < BK; ++kk) {
            const float* as = &As[kk * LDA];
            const float* bs = &Bs[kk * BN];
            float4 af[RM], bf[RN];
#pragma unroll
            for (int i = 0; i < RM; ++i) af[i] = *(const float4*)(as + ar + 32 * i);
#pragma unroll
            for (int j = 0; j < RN; ++j) bf[j] = *(const float4*)(bs + bc + 32 * j);
#pragma unroll
            for (int i = 0; i < RM; ++i) {
                float ae[4] = {af[i].x, af[i].y, af[i].z, af[i].w};
#pragma unroll
                for (int r = 0; r < 4; ++r)
#pragma unroll
                    for (int j = 0; j < RN; ++j)
                        fma4(acc[i][j][r], ae[r], bf[j]);
            }
        }
        __syncthreads();
    }

    // ---- epilogue ----
#pragma unroll
    for (int i = 0; i < RM; ++i)
#pragma unroll
        for (int r = 0; r < 4; ++r) {
            int gr = m0 + ar + 32 * i + r;
            if (gr >= M) continue;
#pragma unroll
            for (int j = 0; j < RN; ++j) {
                int gc = n0 + bc + 32 * j;
                float4 v = acc[i][j][r];
                if (gc + 3 < N) {
                    if (bias) {
                        v.x += bias[gc + 0];
                        v.y += bias[gc + 1];
                        v.z += bias[gc + 2];
                        v.w += bias[gc + 3];
                    }
                    *(float4*)(C + (size_t)gr * N + gc) = v;
                } else {
                    float vv[4] = {v.x, v.y, v.z, v.w};
#pragma unroll
                    for (int e = 0; e < 4; ++e)
                        if (gc + e < N)
                            C[(size_t)gr * N + gc + e] = vv[e] + (bias ? bias[gc + e] : 0.f);
                }
            }
        }
}

// ---------------- launch ----------------
// Harness passes integer inputs as int32. d_out (400 MB) doubles as scratch:
//   O0 h[N,128] | O1 h1[N,128] | O2 h2pre[N,64] | csr_src[E] | offs[N]
//   cursor[N] | deg_cnt[N] | bsums[128]          (all dead before final GEMM)
// d_ws: [dinv 0.5MB][h2 25.6MB] — h2 must survive the final GEMM's d_out writes.

extern "C" void kernel_launch(void* const* d_in, const int* in_sizes, int n_in,
                              void* d_out, int out_size, void* d_ws, size_t ws_size,
                              hipStream_t stream)
{
    const float* x   = (const float*)d_in[0];
    const float* W1  = (const float*)d_in[1];
    const float* b1  = (const float*)d_in[2];
    const float* W2  = (const float*)d_in[3];
    const float* b2  = (const float*)d_in[4];
    const float* Wfc = (const float*)d_in[5];
    const float* bfc = (const float*)d_in[6];
    const int*   ei  = (const int*)d_in[7];     // int32 in the harness

    const int Nn = in_sizes[0] / 128;      // 100000 nodes
    const int E  = in_sizes[7] / 2;        // 1600000 edges
    const int* src = ei;
    const int* dst = ei + E;

    char* ws = (char*)d_ws;
    float* dinv = (float*)(ws);                        // Nn floats
    float* h2   = (float*)(ws + 512 * 1024);           // Nn*64 floats (25.6 MB)

    float* out = (float*)d_out;
    float* O0      = out;                              // h [Nn,128]
    float* O1      = out + (size_t)Nn * 128;           // h1 [Nn,128]
    float* O2      = out + (size_t)Nn * 256;           // h2pre [Nn,64]
    int*   csr_src = (int*)(out + (size_t)Nn * 320);   // E ints
    int*   offs    = (int*)((char*)csr_src + (size_t)E * 4);
    int*   cursor  = (int*)((char*)offs + (size_t)Nn * 4);
    int*   deg_cnt = (int*)((char*)cursor + (size_t)Nn * 4);
    int*   bsums   = (int*)((char*)deg_cnt + (size_t)Nn * 4);

    const int nScanBlocks = (Nn + SCAN_B - 1) / SCAN_B;   // 98 <= 128

    // ---- degree, dinv, offsets, cursor ----
    k_zero_i<<<128, 256, 0, stream>>>(deg_cnt, Nn);
    k_deg_i<<<(E + 255) / 256, 256, 0, stream>>>(dst, deg_cnt, E);
    k_dinv<<<(Nn + 255) / 256, 256, 0, stream>>>(deg_cnt, dinv, Nn);
    k_scan1<<<nScanBlocks, SCAN_B, 0, stream>>>(deg_cnt, offs, bsums, Nn);
    k_scan2<<<1, 128, 0, stream>>>(bsums, nScanBlocks);
    k_scan3<<<nScanBlocks, SCAN_B, 0, stream>>>(offs, cursor, bsums, Nn);

    // ---- CSR fill ----
    k_fill<<<(E + 255) / 256, 256, 0, stream>>>(src, dst, cursor, csr_src, E);

    // ---- layer 1 ----
    // h = x @ W1 -> O0   (BM=256, BN=128, K=128)
    gemm_wt<2, 2, 32, 4, 2><<<dim3((Nn + 255) / 256, 1), 256, 0, stream>>>(
        x, W1, nullptr, O0, Nn, 128, 128);
    // h1 = relu(gather(h) + self + b1) -> O1
    k_gather<128><<<(Nn + 3) / 4, 256, 0, stream>>>(O0, csr_src, offs, dinv, b1, O1, Nn, E);

    // ---- layer 2 ----
    // h2pre = h1 @ W2 -> O2   (BM=256, BN=64, K=128)
    gemm_wt<2, 2, 32, 4, 1><<<dim3((Nn + 255) / 256, 1), 256, 0, stream>>>(
        O1, W2, nullptr, O2, Nn, 64, 128);
    // h2 = relu(gather(h2pre) + self + b2) -> ws
    k_gather<64><<<(Nn + 3) / 4, 256, 0, stream>>>(O2, csr_src, offs, dinv, b2, h2, Nn, E);

    // ---- output layer: out = h2 @ Wfc + bfc  (BM=256, BN=128, K=64) ----
    gemm_wt<2, 2, 32, 4, 2><<<dim3((Nn + 255) / 256, (1000 + 127) / 128), 256, 0, stream>>>(
        h2, Wfc, bfc, out, Nn, 1000, 64);
}